// Round 5
// baseline (310.481 us; speedup 1.0000x reference)
//
#include <hip/hip_runtime.h>
#include <hip/hip_bf16.h>
#include <math.h>

#define B 64
#define N 512
#define C 1024
#define K_NEIGH 32
// Band half-width: need DELTA - bisect_window/2 - E' > E', where
// E' = E_gemm + E_store. E_gemm ~ 0.15 (9-sigma fp16-hi GEMM error);
// E_store <= 0.07 (fp16 storage rounding for band-relevant |v| <= 256).
// window = 2800/2^12 = 0.68 -> DELTA > 0.34 + 0.44 = 0.78; DELTA = 0.9.
// Non-band elements are strictly separated from the true rank-32 cut;
// band candidates are exactly rechecked in fp32 (bitwise-matching dots).
#define DELTA 0.9f
#define BISECT_ITERS 12

typedef __attribute__((ext_vector_type(8))) _Float16 half8;
typedef __attribute__((ext_vector_type(4))) float f32x4;

__device__ __forceinline__ half8 cvt8(float4 a, float4 b) {
    half8 g;
    g[0] = (_Float16)a.x; g[1] = (_Float16)a.y; g[2] = (_Float16)a.z; g[3] = (_Float16)a.w;
    g[4] = (_Float16)b.x; g[5] = (_Float16)b.y; g[6] = (_Float16)b.z; g[7] = (_Float16)b.w;
    return g;
}

// one K-step of MFMA on a staged buffer (64x64 wave tile, 4x4 of 16x16x32)
__device__ __forceinline__ void mfma_step(const half8* __restrict__ Ab,
                                          const half8* __restrict__ Bb,
                                          f32x4 (&acc)[4][4],
                                          int quad, int lid, int wr, int wc) {
    half8 vb[4];
#pragma unroll
    for (int c = 0; c < 4; c++) vb[c] = Bb[quad * 256 + wc + c * 16 + lid];
    __builtin_amdgcn_s_setprio(1);
#pragma unroll
    for (int r = 0; r < 4; r++) {
        half8 va = Ab[quad * 256 + wr + r * 16 + lid];
#pragma unroll
        for (int c = 0; c < 4; c++)
            acc[r][c] = __builtin_amdgcn_mfma_f32_16x16x32_f16(va, vb[c], acc[r][c], 0, 0, 0);
    }
    __builtin_amdgcn_s_setprio(0);
}

// ---------------------------------------------------------------------------
// Kernel 1: S16[b] = fp16( fp16(x[b]) * fp16(x[b])^T ) via f16 MFMA.
// 256x256 tile (best measured config, r3: 79us), 1024 thr = 16 waves (4x4 of
// 64x64), BK=32, distance-2 prefetch + LDS double buffer, ONE barrier/step:
//   body A: issue loads(t+2)->X | MFMA buf0(t) | cvt+write Y(t+1)->buf1 | bar
//   body B: issue loads(t+3)->Y | MFMA buf1    | cvt+write X      ->buf0 | bar
// The cvt's vmcnt wait targets loads issued a FULL K-step earlier (~6000cy),
// so global latency is fully hidden (r3 issued them only ~160cy ahead).
// 16 waves = 4 waves/SIMD restores intra-block TLP (r3 had 2/SIMD, occ 21%).
// Traffic identical to r3; r4's 128^2 regression (traffic x2, spills) avoided.
// LDS granule layout (proven): granule (s,row) = 8 fp16 of k=s*8.. at index
// s*256+row; frag read = 16 consecutive granules = 256B, conflict-free.
// A-frag: A[m=lane&15][k=quad*8+j]; C/D: col=lane&15, row=quad*4+reg.
// ---------------------------------------------------------------------------
__global__ __launch_bounds__(1024, 4) void gemm_f16(const float* __restrict__ x,
                                                    _Float16* __restrict__ S16) {
    __shared__ half8 Ah[2][1024];   // 2 x 16KB (4 granule-cols x 256 rows)
    __shared__ half8 Bh[2][1024];   // 2 x 16KB

    // XCD-aware swizzle: XCD = id%8 owns batches xcd*8..+7 (4 tiles each
    // consecutive) -> tiles of one batch co-resident, share x[b] in L2.
    const int id   = blockIdx.x;           // 0..255
    const int xcd  = id & 7;
    const int slot = id >> 3;              // 0..31
    const int b    = xcd * 8 + (slot >> 2);
    const int tile = slot & 3;
    const int ti = tile >> 1, tj = tile & 1;
    const int row0 = ti * 256;
    const int col0 = tj * 256;
    const float* xb = x + (size_t)b * N * C;
    const bool diag = (ti == tj);

    const int t    = threadIdx.x;
    const int w    = t >> 6;
    const int lane = t & 63;
    const int quad = lane >> 4;
    const int lid  = lane & 15;
    const int wr   = (w >> 2) * 64;        // 4 wave-rows of 64
    const int wc   = (w & 3) * 64;         // 4 wave-cols of 64

    // staging: thread t -> row (t>>2), granule (t&3) = 8 floats of k
    const int srow = t >> 2;
    const int sg   = t & 3;
    const int gidx = sg * 256 + srow;
    const int koff = sg * 8;

    f32x4 acc[4][4];
#pragma unroll
    for (int r = 0; r < 4; r++)
#pragma unroll
        for (int c = 0; c < 4; c++)
#pragma unroll
            for (int e = 0; e < 4; e++) acc[r][c][e] = 0.f;

    const float* pArow = xb + (size_t)(row0 + srow) * C + koff;
    const float* pBrow = xb + (size_t)(col0 + srow) * C + koff;

#define LOADX(A0, A1, B0, B1, step)                                          \
    {                                                                        \
        const float4* pa = (const float4*)(pArow + (step) * 32);             \
        A0 = pa[0]; A1 = pa[1];                                              \
        if (!diag) {                                                         \
            const float4* pb = (const float4*)(pBrow + (step) * 32);         \
            B0 = pb[0]; B1 = pb[1];                                          \
        }                                                                    \
    }
#define STOREX(buf, A0, A1, B0, B1)                                          \
    {                                                                        \
        Ah[buf][gidx] = cvt8(A0, A1);                                        \
        if (!diag) Bh[buf][gidx] = cvt8(B0, B1);                             \
    }

    float4 Xa0, Xa1, Xb0, Xb1, Ya0, Ya1, Yb0, Yb1;

    // ---- prologue: stage step 0, issue step 1 ----
    LOADX(Xa0, Xa1, Xb0, Xb1, 0);
    STOREX(0, Xa0, Xa1, Xb0, Xb1);
    LOADX(Ya0, Ya1, Yb0, Yb1, 1);
    __syncthreads();

    const int NIT = C / 32;                 // 32 K-steps (even)
    for (int it = 0; it < NIT - 2; it += 2) {
        // body A: compute step it (buf0); write step it+1; load step it+2
        LOADX(Xa0, Xa1, Xb0, Xb1, it + 2);
        mfma_step(&Ah[0][0], diag ? &Ah[0][0] : &Bh[0][0], acc, quad, lid, wr, wc);
        STOREX(1, Ya0, Ya1, Yb0, Yb1);
        __syncthreads();
        // body B: compute step it+1 (buf1); write step it+2; load step it+3
        LOADX(Ya0, Ya1, Yb0, Yb1, it + 3);
        mfma_step(&Ah[1][0], diag ? &Ah[1][0] : &Bh[1][0], acc, quad, lid, wr, wc);
        STOREX(0, Xa0, Xa1, Xb0, Xb1);
        __syncthreads();
    }
    // epilogue: steps NIT-2 (buf0) and NIT-1 (buf1)
    mfma_step(&Ah[0][0], diag ? &Ah[0][0] : &Bh[0][0], acc, quad, lid, wr, wc);
    STOREX(1, Ya0, Ya1, Yb0, Yb1);
    __syncthreads();
    mfma_step(&Ah[1][0], diag ? &Ah[1][0] : &Bh[1][0], acc, quad, lid, wr, wc);

#undef LOADX
#undef STOREX

    _Float16* Sb = S16 + (size_t)b * N * N;
#pragma unroll
    for (int r = 0; r < 4; r++) {
#pragma unroll
        for (int c = 0; c < 4; c++) {
#pragma unroll
            for (int e = 0; e < 4; e++) {
                const int grow = row0 + wr + r * 16 + quad * 4 + e;
                const int gcol = col0 + wc + c * 16 + lid;
                Sb[(size_t)grow * N + gcol] = (_Float16)acc[r][c][e];
            }
        }
    }
}

// ---------------------------------------------------------------------------
// Kernel 2: per row -- ballot-popcount bisection for a pivot P with
// #{S' > P+d} <= 31 and #{S' >= P-d} >= 32; band [P-d, P+d] rechecked with
// wave-cooperative exact fp32 dots; exact threshold among band; emit
// 512-bit adjacency mask + deg^-0.5. One wave per row, 4 rows/block.
// S' is fp16; decisions on fp16 values are conservative per the DELTA budget.
// ---------------------------------------------------------------------------
__global__ __launch_bounds__(256) void thresh_mask(const _Float16* __restrict__ S16,
                                                   const float* __restrict__ x,
                                                   unsigned long long* __restrict__ masks,
                                                   float* __restrict__ dinv) {
    // XCD-aware swizzle: XCD = id%8 owns batches xcd*8..+7, so each XCD's
    // band dots re-read its own 2MB x[b] slice from its private L2.
    const int id   = blockIdx.x;               // 0..8191
    const int xcd  = id & 7;
    const int slot = id >> 3;                  // 0..1023
    const int bsw  = xcd * 8 + (slot >> 7);    // batch
    const int rblk = slot & 127;               // 4-row block within batch
    const int row  = bsw * N + rblk * 4 + (threadIdx.x >> 6);
    const int lane = threadIdx.x & 63;
    const _Float16* Srow = S16 + (size_t)row * N;

    float v0[8];
#pragma unroll
    for (int k = 0; k < 8; k++) v0[k] = (float)Srow[lane + 64 * k];   // col = lane + 64k

    // --- bisection: invariant cnt(lo) >= 32, cnt(hi) <= 31, cnt(p)=#{v>p} ---
    float lo = -1400.f, hi = 1400.f;   // |S'| <= ~1300 (diag chi2 max) + margin
    for (int it = 0; it < BISECT_ITERS; it++) {
        const float mid = 0.5f * (lo + hi);
        int c = 0;
#pragma unroll
        for (int k = 0; k < 8; k++) c += __popcll(__ballot(v0[k] > mid));
        if (c >= K_NEIGH) lo = mid; else hi = mid;
    }
    const float P   = 0.5f * (lo + hi);
    const float hiB = P + DELTA, loB = P - DELTA;

    // certainly-in count (<= 31 by construction: hiB > hi)
    int cA = 0;
#pragma unroll
    for (int k = 0; k < 8; k++) cA += __popcll(__ballot(v0[k] > hiB));
    const int m_need = K_NEIGH - cA;   // >= 1 (loB < lo)

    // band candidates: one per lane
    int cnt = 0, myj = -1;
#pragma unroll
    for (int kq = 0; kq < 8; kq++) {
        unsigned long long bm = __ballot(v0[kq] >= loB && v0[kq] <= hiB);
        while (bm) {
            int bl = __ffsll(bm) - 1;
            bm &= bm - 1;
            if (cnt == lane) myj = bl + 64 * kq;
            cnt++;
        }
    }
    const int nc = cnt < 64 ? cnt : 64;

    // wave-cooperative exact dots: lane holds xi[q*256 + lane*4 .. +3]
    const int bb_ = row >> 9, ii = row & (N - 1);
    const float* xi = x + ((size_t)bb_ * N + ii) * C;
    float4 ai[4];
#pragma unroll
    for (int q = 0; q < 4; q++) ai[q] = *(const float4*)(xi + q * 256 + lane * 4);

    float ex = -INFINITY;
    for (int c2 = 0; c2 < nc; c2++) {
        const int j = __shfl(myj, c2);
        const float* xj = x + ((size_t)bb_ * N + j) * C;
        float s = 0.f;
#pragma unroll
        for (int q = 0; q < 4; q++) {
            float4 bv = *(const float4*)(xj + q * 256 + lane * 4);
            s = fmaf(ai[q].x, bv.x, s);
            s = fmaf(ai[q].y, bv.y, s);
            s = fmaf(ai[q].z, bv.z, s);
            s = fmaf(ai[q].w, bv.w, s);
        }
#pragma unroll
        for (int off = 32; off > 0; off >>= 1) s += __shfl_xor(s, off);
        if (lane == c2) ex = s;   // deterministic per (i,j)
    }

    // exact threshold T = m_need-th largest band value (tie-correct)
    float val = ex, T = -INFINITY;
    for (int it = 0; it < m_need; it++) {
        float M = val;
#pragma unroll
        for (int off = 32; off > 0; off >>= 1) M = fmaxf(M, __shfl_xor(M, off));
        T = M;
        unsigned long long ball = __ballot(val == M);
        int first = __ffsll(ball) - 1;
        if (lane == first) val = -INFINITY;
    }
    const int dec = (lane < nc && ex >= T) ? 1 : 0;

    // adjacency bits: certain-above -> 1, band -> exact decision, else 0
    int bits[8];
#pragma unroll
    for (int kq = 0; kq < 8; kq++) bits[kq] = (v0[kq] > hiB) ? 1 : 0;
    for (int c2 = 0; c2 < nc; c2++) {
        int j = __shfl(myj, c2);
        int d = __shfl(dec, c2);
        if ((j & 63) == lane) bits[j >> 6] = d;
    }

    unsigned long long msk[8];
    int deg = 0;
#pragma unroll
    for (int kq = 0; kq < 8; kq++) {
        msk[kq] = __ballot(bits[kq] != 0);
        deg += __popcll(msk[kq]);
    }
    if (lane == 0) {
#pragma unroll
        for (int kq = 0; kq < 8; kq++) masks[(size_t)row * 8 + kq] = msk[kq];
        dinv[row] = rsqrtf((float)deg);
    }
}

// ---------------------------------------------------------------------------
// Kernel 3: out[b,i,j] = maskbit ? dinv[b,i]*dinv[b,j] : 0
// ---------------------------------------------------------------------------
__global__ __launch_bounds__(256) void scale_adj(float* __restrict__ Sout,
                                                 const unsigned long long* __restrict__ masks,
                                                 const float* __restrict__ dinv) {
    const int idx = blockIdx.x * 256 + threadIdx.x;   // float4 index
    const int jq = idx & 127;
    const int i  = (idx >> 7) & (N - 1);
    const int b  = idx >> 16;
    const int row = (b << 9) | i;
    const int j0 = jq * 4;

    const unsigned long long mk = masks[(size_t)row * 8 + (j0 >> 6)];
    const float di = dinv[row];
    float4 dj = ((const float4*)dinv)[(b << 7) | jq];

    float4 o;
    o.x = ((mk >> ((j0 + 0) & 63)) & 1ull) ? di * dj.x : 0.f;
    o.y = ((mk >> ((j0 + 1) & 63)) & 1ull) ? di * dj.y : 0.f;
    o.z = ((mk >> ((j0 + 2) & 63)) & 1ull) ? di * dj.z : 0.f;
    o.w = ((mk >> ((j0 + 3) & 63)) & 1ull) ? di * dj.w : 0.f;
    ((float4*)Sout)[idx] = o;
}

// ---------------------------------------------------------------------------
extern "C" void kernel_launch(void* const* d_in, const int* in_sizes, int n_in,
                              void* d_out, int out_size, void* d_ws, size_t ws_size,
                              hipStream_t stream) {
    const float* x = (const float*)d_in[0];
    float* out = (float*)d_out;                      // final fp32 output
    _Float16* S16 = (_Float16*)d_out;                // staged fp16 S' (first 33.5MB)
    unsigned long long* masks = (unsigned long long*)d_ws;     // B*N*8 u64 = 2MB
    float* dinv = (float*)(masks + (size_t)B * N * 8);         // B*N floats

    gemm_f16<<<dim3(B * 4), 1024, 0, stream>>>(x, S16);        // 256 blocks = 1/CU
    thresh_mask<<<B * N / 4, 256, 0, stream>>>(S16, x, masks, dinv);
    const int total4 = B * N * N / 4;
    scale_adj<<<total4 / 256, 256, 0, stream>>>(out, masks, dinv);
}

// Round 6
// 271.217 us; speedup vs baseline: 1.1448x; 1.1448x over previous
//
#include <hip/hip_runtime.h>
#include <hip/hip_bf16.h>
#include <math.h>

#define B 64
#define N 512
#define C 1024
#define K_NEIGH 32
// Band half-width: need DELTA - bisect_window/2 - E' > E', where
// E' = E_gemm + E_store. E_gemm ~ 0.15 (9-sigma fp16-hi GEMM error);
// E_store <= 0.07 (fp16 storage rounding for band-relevant |v| <= 256).
// window = 2800/2^12 = 0.68 -> DELTA > 0.34 + 0.44 = 0.78; DELTA = 0.9.
// Non-band elements are strictly separated from the true rank-32 cut;
// band candidates are exactly rechecked in fp32 (bitwise-matching dots).
#define DELTA 0.9f
#define BISECT_ITERS 12

typedef __attribute__((ext_vector_type(8))) _Float16 half8;
typedef __attribute__((ext_vector_type(4))) float f32x4;

__device__ __forceinline__ half8 cvt8(float4 a, float4 b) {
    half8 g;
    g[0] = (_Float16)a.x; g[1] = (_Float16)a.y; g[2] = (_Float16)a.z; g[3] = (_Float16)a.w;
    g[4] = (_Float16)b.x; g[5] = (_Float16)b.y; g[6] = (_Float16)b.z; g[7] = (_Float16)b.w;
    return g;
}

// ---------------------------------------------------------------------------
// Kernel 1: S16[b] = fp16( fp16(x[b]) * fp16(x[b])^T ) via f16 MFMA.
// 256x256 tile, 512 thr = 8 waves (2x4, wave tile 128x64), BK=32 -- exactly
// the r3 geometry (best measured: 79.4us, VGPR 100, no spill). Change vs r3:
// the K-loop is ROTATED to extend load->use distance with zero extra VGPRs:
//   iter t: cvt+ds_write X(t)->buf[t&1]   (X loaded during iter t-1)
//           issue global loads(t+1)->X
//           s_waitcnt lgkmcnt(0); raw s_barrier     <-- vmcnt NOT drained!
//           ds_read frags buf[t&1]; 32 MFMA
// __syncthreads() would emit s_waitcnt vmcnt(0) before s_barrier and drain
// the prefetch (the m97-class structural stall); the raw-barrier form keeps
// the 8 loads in flight across the barrier, giving them barrier+ds_read+MFMA
// (~300+cy) of cover instead of ~160cy. Races: STORE(t) vs read(t) separated
// by barrier(t); STORE(t+2)->buf[t&1] vs read(t) separated by barrier(t+1)
// (a wave reaches barrier(t+1) only after its read(t) completed).
// r4 lesson: smaller tiles/more blocks = 2x traffic, net loss. r5 lesson:
// dist-2 at 1024thr spilled (WRITE_SIZE 100MB); this variant adds 0 registers.
// LDS granule layout (proven): granule (s,row) = 8 fp16 of k=s*8.. at index
// s*256+row; frag read = 16 consecutive granules = 256B, conflict-free.
// A-frag: A[m=lane&15][k=quad*8+j]; C/D: col=lane&15, row=quad*4+reg.
// ---------------------------------------------------------------------------
__global__ __launch_bounds__(512, 2) void gemm_f16(const float* __restrict__ x,
                                                   _Float16* __restrict__ S16) {
    __shared__ half8 Ah[2][1024];   // 2 x 16KB (4 granule-cols x 256 rows)
    __shared__ half8 Bh[2][1024];   // 2 x 16KB

    // XCD-aware swizzle: XCD = id%8 owns batches xcd*8..+7 (4 tiles each
    // consecutive) -> tiles of one batch co-resident, share x[b] in L2.
    const int id   = blockIdx.x;           // 0..255
    const int xcd  = id & 7;
    const int slot = id >> 3;              // 0..31
    const int b    = xcd * 8 + (slot >> 2);
    const int tile = slot & 3;
    const int ti = tile >> 1, tj = tile & 1;
    const int row0 = ti * 256;
    const int col0 = tj * 256;
    const float* xb = x + (size_t)b * N * C;
    const bool diag = (ti == tj);

    const int t    = threadIdx.x;
    const int w    = t >> 6;
    const int lane = t & 63;
    const int quad = lane >> 4;
    const int lid  = lane & 15;
    const int wr   = (w >> 2) * 128;       // 2 wave-rows of 128
    const int wc   = (w & 3) * 64;         // 4 wave-cols of 64

    // staging: thread t -> row (t>>1), k-half (t&1)*16 floats (granules s0,s0+1)
    const int srow = t >> 1;
    const int s0   = (t & 1) * 2;
    const int koff = (t & 1) * 16;

    f32x4 acc[8][4];
#pragma unroll
    for (int r = 0; r < 8; r++)
#pragma unroll
        for (int c = 0; c < 4; c++)
#pragma unroll
            for (int e = 0; e < 4; e++) acc[r][c][e] = 0.f;

    const float* pArow = xb + (size_t)(row0 + srow) * C + koff;
    const float* pBrow = xb + (size_t)(col0 + srow) * C + koff;

    float4 ra[4], rb[4];
    // ---- prologue: issue loads for step 0 ----
    {
        const float4* pa = (const float4*)pArow;
#pragma unroll
        for (int i = 0; i < 4; i++) ra[i] = pa[i];
        if (!diag) {
            const float4* pb = (const float4*)pBrow;
#pragma unroll
            for (int i = 0; i < 4; i++) rb[i] = pb[i];
        }
    }

    const int NIT = C / 32;                 // 32 K-steps
    for (int it = 0; it < NIT; ++it) {
        const int p = it & 1;
        // ---- cvt + ds_write step it (vmcnt waits on loads from iter it-1,
        //      which had a full iteration of cover) ----
        Ah[p][s0 * 256 + srow]       = cvt8(ra[0], ra[1]);
        Ah[p][(s0 + 1) * 256 + srow] = cvt8(ra[2], ra[3]);
        if (!diag) {
            Bh[p][s0 * 256 + srow]       = cvt8(rb[0], rb[1]);
            Bh[p][(s0 + 1) * 256 + srow] = cvt8(rb[2], rb[3]);
        }
        // ---- issue loads for step it+1 (stay in flight across barrier) ----
        if (it + 1 < NIT) {
            const float4* pa = (const float4*)(pArow + (it + 1) * 32);
#pragma unroll
            for (int i = 0; i < 4; i++) ra[i] = pa[i];
            if (!diag) {
                const float4* pb = (const float4*)(pBrow + (it + 1) * 32);
#pragma unroll
                for (int i = 0; i < 4; i++) rb[i] = pb[i];
            }
        }
        // ---- barrier draining LDS only; global prefetch NOT drained ----
        asm volatile("s_waitcnt lgkmcnt(0)" ::: "memory");
        __builtin_amdgcn_s_barrier();
        // ---- compute step it from buf p ----
        const half8* Ab = &Ah[p][0];
        const half8* Bb = diag ? Ab : &Bh[p][0];
        half8 vb[4];
#pragma unroll
        for (int c = 0; c < 4; c++) vb[c] = Bb[quad * 256 + wc + c * 16 + lid];
        __builtin_amdgcn_s_setprio(1);
#pragma unroll
        for (int r = 0; r < 8; r++) {
            half8 va = Ab[quad * 256 + wr + r * 16 + lid];
#pragma unroll
            for (int c = 0; c < 4; c++)
                acc[r][c] = __builtin_amdgcn_mfma_f32_16x16x32_f16(va, vb[c], acc[r][c], 0, 0, 0);
        }
        __builtin_amdgcn_s_setprio(0);
    }

    _Float16* Sb = S16 + (size_t)b * N * N;
#pragma unroll
    for (int r = 0; r < 8; r++) {
#pragma unroll
        for (int c = 0; c < 4; c++) {
#pragma unroll
            for (int e = 0; e < 4; e++) {
                const int grow = row0 + wr + r * 16 + quad * 4 + e;
                const int gcol = col0 + wc + c * 16 + lid;
                Sb[(size_t)grow * N + gcol] = (_Float16)acc[r][c][e];
            }
        }
    }
}

// ---------------------------------------------------------------------------
// Kernel 2: per row -- ballot-popcount bisection for a pivot P with
// #{S' > P+d} <= 31 and #{S' >= P-d} >= 32; band [P-d, P+d] rechecked with
// wave-cooperative exact fp32 dots; exact threshold among band; emit
// 512-bit adjacency mask + deg^-0.5. One wave per row, 4 rows/block.
// S' is fp16; decisions on fp16 values are conservative per the DELTA budget.
// ---------------------------------------------------------------------------
__global__ __launch_bounds__(256) void thresh_mask(const _Float16* __restrict__ S16,
                                                   const float* __restrict__ x,
                                                   unsigned long long* __restrict__ masks,
                                                   float* __restrict__ dinv) {
    // XCD-aware swizzle: XCD = id%8 owns batches xcd*8..+7, so each XCD's
    // band dots re-read its own 2MB x[b] slice from its private L2.
    const int id   = blockIdx.x;               // 0..8191
    const int xcd  = id & 7;
    const int slot = id >> 3;                  // 0..1023
    const int bsw  = xcd * 8 + (slot >> 7);    // batch
    const int rblk = slot & 127;               // 4-row block within batch
    const int row  = bsw * N + rblk * 4 + (threadIdx.x >> 6);
    const int lane = threadIdx.x & 63;
    const _Float16* Srow = S16 + (size_t)row * N;

    float v0[8];
#pragma unroll
    for (int k = 0; k < 8; k++) v0[k] = (float)Srow[lane + 64 * k];   // col = lane + 64k

    // --- bisection: invariant cnt(lo) >= 32, cnt(hi) <= 31, cnt(p)=#{v>p} ---
    float lo = -1400.f, hi = 1400.f;   // |S'| <= ~1300 (diag chi2 max) + margin
    for (int it = 0; it < BISECT_ITERS; it++) {
        const float mid = 0.5f * (lo + hi);
        int c = 0;
#pragma unroll
        for (int k = 0; k < 8; k++) c += __popcll(__ballot(v0[k] > mid));
        if (c >= K_NEIGH) lo = mid; else hi = mid;
    }
    const float P   = 0.5f * (lo + hi);
    const float hiB = P + DELTA, loB = P - DELTA;

    // certainly-in count (<= 31 by construction: hiB > hi)
    int cA = 0;
#pragma unroll
    for (int k = 0; k < 8; k++) cA += __popcll(__ballot(v0[k] > hiB));
    const int m_need = K_NEIGH - cA;   // >= 1 (loB < lo)

    // band candidates: one per lane
    int cnt = 0, myj = -1;
#pragma unroll
    for (int kq = 0; kq < 8; kq++) {
        unsigned long long bm = __ballot(v0[kq] >= loB && v0[kq] <= hiB);
        while (bm) {
            int bl = __ffsll(bm) - 1;
            bm &= bm - 1;
            if (cnt == lane) myj = bl + 64 * kq;
            cnt++;
        }
    }
    const int nc = cnt < 64 ? cnt : 64;

    // wave-cooperative exact dots: lane holds xi[q*256 + lane*4 .. +3]
    const int bb_ = row >> 9, ii = row & (N - 1);
    const float* xi = x + ((size_t)bb_ * N + ii) * C;
    float4 ai[4];
#pragma unroll
    for (int q = 0; q < 4; q++) ai[q] = *(const float4*)(xi + q * 256 + lane * 4);

    float ex = -INFINITY;
    for (int c2 = 0; c2 < nc; c2++) {
        const int j = __shfl(myj, c2);
        const float* xj = x + ((size_t)bb_ * N + j) * C;
        float s = 0.f;
#pragma unroll
        for (int q = 0; q < 4; q++) {
            float4 bv = *(const float4*)(xj + q * 256 + lane * 4);
            s = fmaf(ai[q].x, bv.x, s);
            s = fmaf(ai[q].y, bv.y, s);
            s = fmaf(ai[q].z, bv.z, s);
            s = fmaf(ai[q].w, bv.w, s);
        }
#pragma unroll
        for (int off = 32; off > 0; off >>= 1) s += __shfl_xor(s, off);
        if (lane == c2) ex = s;   // deterministic per (i,j)
    }

    // exact threshold T = m_need-th largest band value (tie-correct)
    float val = ex, T = -INFINITY;
    for (int it = 0; it < m_need; it++) {
        float M = val;
#pragma unroll
        for (int off = 32; off > 0; off >>= 1) M = fmaxf(M, __shfl_xor(M, off));
        T = M;
        unsigned long long ball = __ballot(val == M);
        int first = __ffsll(ball) - 1;
        if (lane == first) val = -INFINITY;
    }
    const int dec = (lane < nc && ex >= T) ? 1 : 0;

    // adjacency bits: certain-above -> 1, band -> exact decision, else 0
    int bits[8];
#pragma unroll
    for (int kq = 0; kq < 8; kq++) bits[kq] = (v0[kq] > hiB) ? 1 : 0;
    for (int c2 = 0; c2 < nc; c2++) {
        int j = __shfl(myj, c2);
        int d = __shfl(dec, c2);
        if ((j & 63) == lane) bits[j >> 6] = d;
    }

    unsigned long long msk[8];
    int deg = 0;
#pragma unroll
    for (int kq = 0; kq < 8; kq++) {
        msk[kq] = __ballot(bits[kq] != 0);
        deg += __popcll(msk[kq]);
    }
    if (lane == 0) {
#pragma unroll
        for (int kq = 0; kq < 8; kq++) masks[(size_t)row * 8 + kq] = msk[kq];
        dinv[row] = rsqrtf((float)deg);
    }
}

// ---------------------------------------------------------------------------
// Kernel 3: out[b,i,j] = maskbit ? dinv[b,i]*dinv[b,j] : 0
// ---------------------------------------------------------------------------
__global__ __launch_bounds__(256) void scale_adj(float* __restrict__ Sout,
                                                 const unsigned long long* __restrict__ masks,
                                                 const float* __restrict__ dinv) {
    const int idx = blockIdx.x * 256 + threadIdx.x;   // float4 index
    const int jq = idx & 127;
    const int i  = (idx >> 7) & (N - 1);
    const int b  = idx >> 16;
    const int row = (b << 9) | i;
    const int j0 = jq * 4;

    const unsigned long long mk = masks[(size_t)row * 8 + (j0 >> 6)];
    const float di = dinv[row];
    float4 dj = ((const float4*)dinv)[(b << 7) | jq];

    float4 o;
    o.x = ((mk >> ((j0 + 0) & 63)) & 1ull) ? di * dj.x : 0.f;
    o.y = ((mk >> ((j0 + 1) & 63)) & 1ull) ? di * dj.y : 0.f;
    o.z = ((mk >> ((j0 + 2) & 63)) & 1ull) ? di * dj.z : 0.f;
    o.w = ((mk >> ((j0 + 3) & 63)) & 1ull) ? di * dj.w : 0.f;
    ((float4*)Sout)[idx] = o;
}

// ---------------------------------------------------------------------------
extern "C" void kernel_launch(void* const* d_in, const int* in_sizes, int n_in,
                              void* d_out, int out_size, void* d_ws, size_t ws_size,
                              hipStream_t stream) {
    const float* x = (const float*)d_in[0];
    float* out = (float*)d_out;                      // final fp32 output
    _Float16* S16 = (_Float16*)d_out;                // staged fp16 S' (first 33.5MB)
    unsigned long long* masks = (unsigned long long*)d_ws;     // B*N*8 u64 = 2MB
    float* dinv = (float*)(masks + (size_t)B * N * 8);         // B*N floats

    gemm_f16<<<dim3(B * 4), 512, 0, stream>>>(x, S16);         // 256 blocks = 1/CU
    thresh_mask<<<B * N / 4, 256, 0, stream>>>(S16, x, masks, dinv);
    const int total4 = B * N * N / 4;
    scale_adj<<<total4 / 256, 256, 0, stream>>>(out, masks, dinv);
}

// Round 7
// 270.090 us; speedup vs baseline: 1.1495x; 1.0042x over previous
//
#include <hip/hip_runtime.h>
#include <hip/hip_bf16.h>
#include <math.h>

#define B 64
#define N 512
#define C 1024
#define K_NEIGH 32
// Band half-width: need DELTA - bisect_window/2 - E' > E', where
// E' = E_gemm + E_store. E_gemm ~ 0.15 (9-sigma fp16-hi GEMM error);
// E_store <= 0.07 (fp16 storage rounding for band-relevant |v| <= 256).
// max window = 2800/2^12 = 0.68 -> DELTA > 0.34 + 0.44 = 0.78; DELTA = 0.9.
// (tight-bracket path: window 20/2^5 = 0.625 -> even stricter separation)
// Non-band elements are strictly separated from the true rank-32 cut;
// band candidates are exactly rechecked in fp32 (bitwise-matching dots).
#define DELTA 0.9f
#define BISECT_ITERS 12

typedef __attribute__((ext_vector_type(8))) _Float16 half8;
typedef __attribute__((ext_vector_type(4))) float f32x4;

__device__ __forceinline__ half8 cvt8(float4 a, float4 b) {
    half8 g;
    g[0] = (_Float16)a.x; g[1] = (_Float16)a.y; g[2] = (_Float16)a.z; g[3] = (_Float16)a.w;
    g[4] = (_Float16)b.x; g[5] = (_Float16)b.y; g[6] = (_Float16)b.z; g[7] = (_Float16)b.w;
    return g;
}

// ---------------------------------------------------------------------------
// Kernel 1: S16[b] = fp16( fp16(x[b]) * fp16(x[b])^T ) via f16 MFMA.
// 256x256 tile, 512 thr = 8 waves (2x4, wave tile 128x64), BK=32, rotated
// 2-phase pipeline with raw barrier (vmcnt NOT drained across it).
// UNCHANGED from round 6 (best measured; reg-staged 2-phase ceiling).
// ---------------------------------------------------------------------------
__global__ __launch_bounds__(512, 2) void gemm_f16(const float* __restrict__ x,
                                                   _Float16* __restrict__ S16) {
    __shared__ half8 Ah[2][1024];   // 2 x 16KB (4 granule-cols x 256 rows)
    __shared__ half8 Bh[2][1024];   // 2 x 16KB

    const int id   = blockIdx.x;           // 0..255
    const int xcd  = id & 7;
    const int slot = id >> 3;              // 0..31
    const int b    = xcd * 8 + (slot >> 2);
    const int tile = slot & 3;
    const int ti = tile >> 1, tj = tile & 1;
    const int row0 = ti * 256;
    const int col0 = tj * 256;
    const float* xb = x + (size_t)b * N * C;
    const bool diag = (ti == tj);

    const int t    = threadIdx.x;
    const int w    = t >> 6;
    const int lane = t & 63;
    const int quad = lane >> 4;
    const int lid  = lane & 15;
    const int wr   = (w >> 2) * 128;       // 2 wave-rows of 128
    const int wc   = (w & 3) * 64;         // 4 wave-cols of 64

    const int srow = t >> 1;
    const int s0   = (t & 1) * 2;
    const int koff = (t & 1) * 16;

    f32x4 acc[8][4];
#pragma unroll
    for (int r = 0; r < 8; r++)
#pragma unroll
        for (int c = 0; c < 4; c++)
#pragma unroll
            for (int e = 0; e < 4; e++) acc[r][c][e] = 0.f;

    const float* pArow = xb + (size_t)(row0 + srow) * C + koff;
    const float* pBrow = xb + (size_t)(col0 + srow) * C + koff;

    float4 ra[4], rb[4];
    {
        const float4* pa = (const float4*)pArow;
#pragma unroll
        for (int i = 0; i < 4; i++) ra[i] = pa[i];
        if (!diag) {
            const float4* pb = (const float4*)pBrow;
#pragma unroll
            for (int i = 0; i < 4; i++) rb[i] = pb[i];
        }
    }

    const int NIT = C / 32;                 // 32 K-steps
    for (int it = 0; it < NIT; ++it) {
        const int p = it & 1;
        Ah[p][s0 * 256 + srow]       = cvt8(ra[0], ra[1]);
        Ah[p][(s0 + 1) * 256 + srow] = cvt8(ra[2], ra[3]);
        if (!diag) {
            Bh[p][s0 * 256 + srow]       = cvt8(rb[0], rb[1]);
            Bh[p][(s0 + 1) * 256 + srow] = cvt8(rb[2], rb[3]);
        }
        if (it + 1 < NIT) {
            const float4* pa = (const float4*)(pArow + (it + 1) * 32);
#pragma unroll
            for (int i = 0; i < 4; i++) ra[i] = pa[i];
            if (!diag) {
                const float4* pb = (const float4*)(pBrow + (it + 1) * 32);
#pragma unroll
                for (int i = 0; i < 4; i++) rb[i] = pb[i];
            }
        }
        asm volatile("s_waitcnt lgkmcnt(0)" ::: "memory");
        __builtin_amdgcn_s_barrier();
        const half8* Ab = &Ah[p][0];
        const half8* Bb = diag ? Ab : &Bh[p][0];
        half8 vb[4];
#pragma unroll
        for (int c = 0; c < 4; c++) vb[c] = Bb[quad * 256 + wc + c * 16 + lid];
        __builtin_amdgcn_s_setprio(1);
#pragma unroll
        for (int r = 0; r < 8; r++) {
            half8 va = Ab[quad * 256 + wr + r * 16 + lid];
#pragma unroll
            for (int c = 0; c < 4; c++)
                acc[r][c] = __builtin_amdgcn_mfma_f32_16x16x32_f16(va, vb[c], acc[r][c], 0, 0, 0);
        }
        __builtin_amdgcn_s_setprio(0);
    }

    _Float16* Sb = S16 + (size_t)b * N * N;
#pragma unroll
    for (int r = 0; r < 8; r++) {
#pragma unroll
        for (int c = 0; c < 4; c++) {
#pragma unroll
            for (int e = 0; e < 4; e++) {
                const int grow = row0 + wr + r * 16 + quad * 4 + e;
                const int gcol = col0 + wc + c * 16 + lid;
                Sb[(size_t)grow * N + gcol] = (_Float16)acc[r][c][e];
            }
        }
    }
}

// ---------------------------------------------------------------------------
// Kernel 2: per row -- pivot P via ballot-popcount bisection; band [P-d,P+d]
// rechecked with wave-cooperative exact fp32 dots; exact threshold among
// band; emit 512-bit adjacency mask + deg^-0.5. One wave/row, 4 rows/block.
// Round-7 changes (exactness-preserving):
//  * sigma-quantile bracket: P_est = 1.542*sigma_row (diag excluded); if
//    cnt(P_est-10)>=32 && cnt(P_est+10)<=31 the bisection runs 5 iters on
//    [P_est-10, P_est+10] (window 0.625), else wide 12-iter fallback.
//    Validity is CHECKED, so the invariant is unconditional.
//  * band dots: 2 candidates per iteration (independent fma chains + two
//    interleaved reduces) -- per-candidate fp32 value bit-identical to the
//    single-candidate version (same fma order, same reduce tree).
//  * ai (xi fragments) hoisted before the bisection: ~500cy of L2 latency
//    drains under ballot compute.
// ---------------------------------------------------------------------------
__global__ __launch_bounds__(256) void thresh_mask(const _Float16* __restrict__ S16,
                                                   const float* __restrict__ x,
                                                   unsigned long long* __restrict__ masks,
                                                   float* __restrict__ dinv) {
    // XCD-aware swizzle: XCD = id%8 owns batches xcd*8..+7, so each XCD's
    // band dots re-read its own 2MB x[b] slice from its private L2.
    const int id   = blockIdx.x;               // 0..8191
    const int xcd  = id & 7;
    const int slot = id >> 3;                  // 0..1023
    const int bsw  = xcd * 8 + (slot >> 7);    // batch
    const int rblk = slot & 127;               // 4-row block within batch
    const int row  = bsw * N + rblk * 4 + (threadIdx.x >> 6);
    const int lane = threadIdx.x & 63;
    const _Float16* Srow = S16 + (size_t)row * N;

    const int bb_ = row >> 9, ii = row & (N - 1);
    const float* xi = x + ((size_t)bb_ * N + ii) * C;

    float v0[8];
#pragma unroll
    for (int k = 0; k < 8; k++) v0[k] = (float)Srow[lane + 64 * k];   // col = lane + 64k

    // hoisted xi fragments (latency hides under the ballot work below)
    float4 ai[4];
#pragma unroll
    for (int q = 0; q < 4; q++) ai[q] = *(const float4*)(xi + q * 256 + lane * 4);

    // --- sigma-based bracket estimate (diagonal excluded) ---
    float sum2 = 0.f;
#pragma unroll
    for (int k = 0; k < 8; k++) {
        const float v = ((lane + 64 * k) == ii) ? 0.f : v0[k];
        sum2 = fmaf(v, v, sum2);
    }
#pragma unroll
    for (int off = 32; off > 0; off >>= 1) sum2 += __shfl_xor(sum2, off);
    const float Pest = 1.542f * sqrtf(sum2 * (1.0f / 511.0f));
    const float bhi = Pest + 10.f, blo = Pest - 10.f;
    int chk_hi = 0, chk_lo = 0;
#pragma unroll
    for (int k = 0; k < 8; k++) {
        chk_hi += __popcll(__ballot(v0[k] > bhi));
        chk_lo += __popcll(__ballot(v0[k] > blo));
    }

    // --- bisection: invariant cnt(lo) >= 32, cnt(hi) <= 31, cnt(p)=#{v>p} ---
    float lo, hi;
    int nit;
    if (chk_hi <= K_NEIGH - 1 && chk_lo >= K_NEIGH) {
        lo = blo; hi = bhi; nit = 5;               // window 20/32 = 0.625
    } else {
        lo = -1400.f; hi = 1400.f; nit = BISECT_ITERS;   // window 0.684
    }
    for (int it = 0; it < nit; it++) {
        const float mid = 0.5f * (lo + hi);
        int c = 0;
#pragma unroll
        for (int k = 0; k < 8; k++) c += __popcll(__ballot(v0[k] > mid));
        if (c >= K_NEIGH) lo = mid; else hi = mid;
    }
    const float P   = 0.5f * (lo + hi);
    const float hiB = P + DELTA, loB = P - DELTA;

    // certainly-in count (<= 31 by construction: hiB > hi)
    int cA = 0;
#pragma unroll
    for (int k = 0; k < 8; k++) cA += __popcll(__ballot(v0[k] > hiB));
    const int m_need = K_NEIGH - cA;   // >= 1 (loB < lo)

    // band candidates: one per lane
    int cnt = 0, myj = -1;
#pragma unroll
    for (int kq = 0; kq < 8; kq++) {
        unsigned long long bm = __ballot(v0[kq] >= loB && v0[kq] <= hiB);
        while (bm) {
            int bl = __ffsll(bm) - 1;
            bm &= bm - 1;
            if (cnt == lane) myj = bl + 64 * kq;
            cnt++;
        }
    }
    const int nc = cnt < 64 ? cnt : 64;

    // wave-cooperative exact dots, 2 candidates per pass (ILP); per-candidate
    // fma/reduce order identical to the serial version -> same fp32 values.
    float ex = -INFINITY;
    for (int c2 = 0; c2 < nc; c2 += 2) {
        const int c3 = (c2 + 1 < nc) ? c2 + 1 : c2;
        const int j0 = __shfl(myj, c2);
        const int j1 = __shfl(myj, c3);
        const float* xj0 = x + ((size_t)bb_ * N + j0) * C;
        const float* xj1 = x + ((size_t)bb_ * N + j1) * C;
        float s0 = 0.f, s1 = 0.f;
#pragma unroll
        for (int q = 0; q < 4; q++) {
            float4 b0 = *(const float4*)(xj0 + q * 256 + lane * 4);
            float4 b1 = *(const float4*)(xj1 + q * 256 + lane * 4);
            s0 = fmaf(ai[q].x, b0.x, s0);
            s0 = fmaf(ai[q].y, b0.y, s0);
            s0 = fmaf(ai[q].z, b0.z, s0);
            s0 = fmaf(ai[q].w, b0.w, s0);
            s1 = fmaf(ai[q].x, b1.x, s1);
            s1 = fmaf(ai[q].y, b1.y, s1);
            s1 = fmaf(ai[q].z, b1.z, s1);
            s1 = fmaf(ai[q].w, b1.w, s1);
        }
#pragma unroll
        for (int off = 32; off > 0; off >>= 1) {
            s0 += __shfl_xor(s0, off);
            s1 += __shfl_xor(s1, off);
        }
        if (lane == c2) ex = s0;
        if (lane == c3 && c3 != c2) ex = s1;
    }

    // exact threshold T = m_need-th largest band value (tie-correct)
    float val = ex, T = -INFINITY;
    for (int it = 0; it < m_need; it++) {
        float M = val;
#pragma unroll
        for (int off = 32; off > 0; off >>= 1) M = fmaxf(M, __shfl_xor(M, off));
        T = M;
        unsigned long long ball = __ballot(val == M);
        int first = __ffsll(ball) - 1;
        if (lane == first) val = -INFINITY;
    }
    const int dec = (lane < nc && ex >= T) ? 1 : 0;

    // adjacency bits: certain-above -> 1, band -> exact decision, else 0
    int bits[8];
#pragma unroll
    for (int kq = 0; kq < 8; kq++) bits[kq] = (v0[kq] > hiB) ? 1 : 0;
    for (int c2 = 0; c2 < nc; c2++) {
        int j = __shfl(myj, c2);
        int d = __shfl(dec, c2);
        if ((j & 63) == lane) bits[j >> 6] = d;
    }

    unsigned long long msk[8];
    int deg = 0;
#pragma unroll
    for (int kq = 0; kq < 8; kq++) {
        msk[kq] = __ballot(bits[kq] != 0);
        deg += __popcll(msk[kq]);
    }
    if (lane == 0) {
#pragma unroll
        for (int kq = 0; kq < 8; kq++) masks[(size_t)row * 8 + kq] = msk[kq];
        dinv[row] = rsqrtf((float)deg);
    }
}

// ---------------------------------------------------------------------------
// Kernel 3: out[b,i,j] = maskbit ? dinv[b,i]*dinv[b,j] : 0
// ---------------------------------------------------------------------------
__global__ __launch_bounds__(256) void scale_adj(float* __restrict__ Sout,
                                                 const unsigned long long* __restrict__ masks,
                                                 const float* __restrict__ dinv) {
    const int idx = blockIdx.x * 256 + threadIdx.x;   // float4 index
    const int jq = idx & 127;
    const int i  = (idx >> 7) & (N - 1);
    const int b  = idx >> 16;
    const int row = (b << 9) | i;
    const int j0 = jq * 4;

    const unsigned long long mk = masks[(size_t)row * 8 + (j0 >> 6)];
    const float di = dinv[row];
    float4 dj = ((const float4*)dinv)[(b << 7) | jq];

    float4 o;
    o.x = ((mk >> ((j0 + 0) & 63)) & 1ull) ? di * dj.x : 0.f;
    o.y = ((mk >> ((j0 + 1) & 63)) & 1ull) ? di * dj.y : 0.f;
    o.z = ((mk >> ((j0 + 2) & 63)) & 1ull) ? di * dj.z : 0.f;
    o.w = ((mk >> ((j0 + 3) & 63)) & 1ull) ? di * dj.w : 0.f;
    ((float4*)Sout)[idx] = o;
}

// ---------------------------------------------------------------------------
extern "C" void kernel_launch(void* const* d_in, const int* in_sizes, int n_in,
                              void* d_out, int out_size, void* d_ws, size_t ws_size,
                              hipStream_t stream) {
    const float* x = (const float*)d_in[0];
    float* out = (float*)d_out;                      // final fp32 output
    _Float16* S16 = (_Float16*)d_out;                // staged fp16 S' (first 33.5MB)
    unsigned long long* masks = (unsigned long long*)d_ws;     // B*N*8 u64 = 2MB
    float* dinv = (float*)(masks + (size_t)B * N * 8);         // B*N floats

    gemm_f16<<<dim3(B * 4), 512, 0, stream>>>(x, S16);         // 256 blocks = 1/CU
    thresh_mask<<<B * N / 4, 256, 0, stream>>>(S16, x, masks, dinv);
    const int total4 = B * N * N / 4;
    scale_adj<<<total4 / 256, 256, 0, stream>>>(out, masks, dinv);
}